// Round 7
// baseline (790.163 us; speedup 1.0000x reference)
//
#include <hip/hip_runtime.h>

// SRU forward: u = x@W (only k=0,1 columns), f = sigmoid(u1+bias), scan
// c_t = (c_{t-1}-x~)*f + x~, h = tanh(c). Outputs: h (L,B,N) then c_final (B,N).
//
// GEMM: 256x256 tile, BK=64, 8-phase schedule (byte-identical to the R4
// version that passed). Scan: single-pass decoupled lookback with scratch at
// ws+196MB (ABOVE all other buffers -- the R5/R6 crashes were the scratch
// living inside the Abf region and the ticket being trampled by cvt_x_k,
// giving wild OOB ci). Falls back to the proven 3-kernel scan if ws_size is
// too small for the high scratch region.
//
// ws layout: [0,64MB) A_bf16  [64,68MB) Bp  [68,196MB) U
//            lookback path:  [196MB,200MB) AV, [200MB,+16KB) flags+ticket
//            3-kernel path:  AV/CS reuse [0,6MB) AFTER gemm (as in R4)

typedef __attribute__((ext_vector_type(8))) short short8;
typedef __attribute__((ext_vector_type(4))) float f32x4;

#define L_SEQ 2048
#define BATCH 16
#define NIN   1024
#define NOUT  1024
#define MROWS (L_SEQ * BATCH)    // 32768
#define NCOLS (2 * NOUT)         // 2048
#define ROWELEMS (BATCH * NOUT)  // 16384
#define NCHUNK 32
#define CHLEN  64
#define NPANEL 64                // 16384 / 256
#define NT 16                    // K-tiles of 64 (K=1024)

__device__ __forceinline__ unsigned short f2bf(float f) {
  unsigned u = __float_as_uint(f);
  u += 0x7fffu + ((u >> 16) & 1u);
  return (unsigned short)(u >> 16);
}
__device__ __forceinline__ float bf2f(unsigned short b) {
  return __uint_as_float(((unsigned)b) << 16);
}
__device__ __forceinline__ float sigmoidf_(float x) {
  return __builtin_amdgcn_rcpf(1.f + __expf(-x));
}
__device__ __forceinline__ float fast_tanh(float x) {
  float ax = fabsf(x);
  float t = __expf(-2.f * ax);
  float r = (1.f - t) * __builtin_amdgcn_rcpf(1.f + t);
  return copysignf(r, x);
}

#define GLL16(gptr, lptr)                                              \
  __builtin_amdgcn_global_load_lds(                                    \
      (const __attribute__((address_space(1))) void*)(gptr),           \
      (__attribute__((address_space(3))) void*)(lptr), 16, 0, 0)

// ---- 1. x fp32 -> bf16 --------------------------------------------------
__global__ __launch_bounds__(256) void cvt_x_k(const float* __restrict__ x,
                                               unsigned short* __restrict__ o) {
  size_t i = ((size_t)blockIdx.x * 256 + threadIdx.x) * 8;
  const float4* p = (const float4*)(x + i);
  float4 a = p[0], b = p[1];
  union { unsigned short s[8]; uint4 v; } r;
  r.s[0] = f2bf(a.x); r.s[1] = f2bf(a.y); r.s[2] = f2bf(a.z); r.s[3] = f2bf(a.w);
  r.s[4] = f2bf(b.x); r.s[5] = f2bf(b.y); r.s[6] = f2bf(b.z); r.s[7] = f2bf(b.w);
  *(uint4*)(o + i) = r.v;
}

// ---- 2. pack W cols {3d,3d+1} -> B^T [n][k], LDS transpose (coalesced) --
__global__ __launch_bounds__(256) void pack_w_k(const float* __restrict__ W,
                                                unsigned short* __restrict__ Bp) {
  __shared__ float tile[64][97];
  int n0 = blockIdx.x * 64;
  int k0 = blockIdx.y * 64;
  int c0 = 3 * (n0 >> 1);         // col window [c0, c0+96)
  int tid = threadIdx.x;
  for (int idx = tid; idx < 64 * 96; idx += 256) {
    int r = idx / 96, c = idx - r * 96;
    tile[r][c] = W[(size_t)(k0 + r) * (3 * NOUT) + c0 + c];
  }
  __syncthreads();
#pragma unroll
  for (int q = 0; q < 2; ++q) {
    int pos = tid * 2 + q;        // 0..511; (n-row, k-chunk) pairs
    int dn = pos >> 3;
    int j8 = (pos & 7) * 8;
    int cl = 3 * (dn >> 1) + (dn & 1);
    union { unsigned short s[8]; uint4 v; } r;
#pragma unroll
    for (int j = 0; j < 8; ++j) r.s[j] = f2bf(tile[j8 + j][cl]);
    *(uint4*)(Bp + (size_t)(n0 + dn) * NIN + k0 + j8) = r.v;
  }
}

// ---- 3. 256x256 8-phase MFMA GEMM (identical to passing R4 version) -----
#define BARR __builtin_amdgcn_s_barrier()
#define SCHED0 __builtin_amdgcn_sched_barrier(0)
#define VMCNT(n) asm volatile("s_waitcnt vmcnt(" #n ")" ::: "memory")

#define STAGE_A(bufc, ha, kt)                                                   \
  do {                                                                          \
    GLL16(pga##ha##0 + (kt) * 64, lds + (bufc) * 32768 + (ha) * 16384 + tid * 16);      \
    GLL16(pga##ha##1 + (kt) * 64, lds + (bufc) * 32768 + (ha) * 16384 + 8192 + tid * 16); \
  } while (0)
#define STAGE_B(bufc, hb, kt)                                                   \
  do {                                                                          \
    GLL16(pgb##hb##0 + (kt) * 64, lds + 65536 + (bufc) * 32768 + (hb) * 16384 + tid * 16); \
    GLL16(pgb##hb##1 + (kt) * 64, lds + 65536 + (bufc) * 32768 + (hb) * 16384 + 8192 + tid * 16); \
  } while (0)

#define LDA(DST, bufc, half)                                                    \
  _Pragma("unroll") for (int i = 0; i < 4; ++i) {                               \
    DST[i][0] = *(const short8*)(lds + (bufc) * 32768 + (half) * 16384 +        \
                                 (rowAb + i * 16) * 128 + colX0);               \
    DST[i][1] = *(const short8*)(lds + (bufc) * 32768 + (half) * 16384 +        \
                                 (rowAb + i * 16) * 128 + colX1);               \
  }
#define LDB(DST, bufc, half)                                                    \
  _Pragma("unroll") for (int j = 0; j < 2; ++j) {                               \
    DST[j][0] = *(const short8*)(lds + 65536 + (bufc) * 32768 + (half) * 16384 + \
                                 (rowBb + j * 16) * 128 + colX0);               \
    DST[j][1] = *(const short8*)(lds + 65536 + (bufc) * 32768 + (half) * 16384 + \
                                 (rowBb + j * 16) * 128 + colX1);               \
  }

#define MM(Q, AF, BF)                                                           \
  _Pragma("unroll") for (int i = 0; i < 4; ++i)                                 \
  _Pragma("unroll") for (int j = 0; j < 2; ++j) {                               \
    Q[i][j] = __builtin_amdgcn_mfma_f32_16x16x32_bf16(AF[i][0], BF[j][0], Q[i][j], 0, 0, 0); \
    Q[i][j] = __builtin_amdgcn_mfma_f32_16x16x32_bf16(AF[i][1], BF[j][1], Q[i][j], 0, 0, 0); \
  }

#define PH_TAIL(Q, AF, BF)                                                      \
  BARR;                                                                         \
  __builtin_amdgcn_s_setprio(1);                                                \
  MM(Q, AF, BF);                                                                \
  __builtin_amdgcn_s_setprio(0);                                                \
  BARR;                                                                         \
  SCHED0

#define PH_TAILV(Q, AF, BF)                                                     \
  BARR;                                                                         \
  __builtin_amdgcn_s_setprio(1);                                                \
  MM(Q, AF, BF);                                                                \
  __builtin_amdgcn_s_setprio(0);                                                \
  VMCNT(4);                                                                     \
  BARR;                                                                         \
  SCHED0

#define EPI(Q, qm, qn)                                                          \
  do {                                                                          \
    _Pragma("unroll") for (int i = 0; i < 4; ++i)                               \
    _Pragma("unroll") for (int j = 0; j < 2; ++j) {                             \
      int n = n0 + (qn) * 128 + wn * 32 + j * 16 + nc;                          \
      float bsel = bias[n >> 1];                                                \
      _Pragma("unroll") for (int r = 0; r < 4; ++r) {                           \
        int m = m0 + (qm) * 128 + wm * 64 + i * 16 + mr + r;                    \
        float v = Q[i][j][r];                                                   \
        if (isf) v = sigmoidf_(v + bsel);                                       \
        U[(size_t)m * NCOLS + n] = f2bf(v);                                     \
      }                                                                         \
    }                                                                           \
  } while (0)

__global__ __launch_bounds__(512, 2) void gemm8_k(const unsigned short* __restrict__ A,
                                                  const unsigned short* __restrict__ B,
                                                  const float* __restrict__ bias,
                                                  unsigned short* __restrict__ U) {
  __shared__ __align__(16) char lds[131072];
  const int K = NIN;
  int tid = threadIdx.x;
  int wave = tid >> 6;
  int lane = tid & 63;
  int wm = wave >> 2;
  int wn = wave & 3;
  int lr = lane & 15;
  int hi = lane >> 4;

  int bi = blockIdx.x;
  int t = (bi & 7) * 128 + (bi >> 3);
  int n0 = (t & 7) << 8;
  int m0 = (t >> 3) << 8;

  int rowAb = wm * 64 + lr;
  int rowBb = wn * 32 + lr;
  int swz = (lr & 7) << 4;
  int colX0 = (hi * 16) ^ swz;
  int colX1 = (64 + hi * 16) ^ swz;

  int row0 = tid >> 3;
  int gch = (tid & 7) ^ (row0 & 7);
  const unsigned short* pga00 = A + (size_t)(m0 + row0) * K + gch * 8;
  const unsigned short* pga01 = pga00 + (size_t)64 * K;
  const unsigned short* pga10 = pga00 + (size_t)128 * K;
  const unsigned short* pga11 = pga00 + (size_t)192 * K;
  const unsigned short* pgb00 = B + (size_t)(n0 + row0) * K + gch * 8;
  const unsigned short* pgb01 = pgb00 + (size_t)64 * K;
  const unsigned short* pgb10 = pgb00 + (size_t)128 * K;
  const unsigned short* pgb11 = pgb00 + (size_t)192 * K;

  f32x4 zero = {0.f, 0.f, 0.f, 0.f};
  f32x4 acc00[4][2], acc01[4][2], acc11[4][2], acc10[4][2];
#pragma unroll
  for (int i = 0; i < 4; ++i)
#pragma unroll
    for (int j = 0; j < 2; ++j) {
      acc00[i][j] = zero; acc01[i][j] = zero;
      acc11[i][j] = zero; acc10[i][j] = zero;
    }

  short8 af[4][2], bq0[2][2], bq1[2][2];

  STAGE_A(0, 0, 0); STAGE_A(0, 1, 0); STAGE_B(0, 0, 0); STAGE_B(0, 1, 0);
  STAGE_A(1, 0, 1); STAGE_B(1, 1, 1);
  VMCNT(4);
  BARR;
  SCHED0;

  for (int it = 0; it < NT / 2; ++it) {
    int kt = it * 2;
    int k1 = kt + 1, k2 = (kt + 2) & (NT - 1), k3 = (kt + 3) & (NT - 1);
    STAGE_B(1, 0, k1); STAGE_A(1, 1, k1);
    LDA(af, 0, 0); LDB(bq0, 0, 0);
    PH_TAIL(acc00, af, bq0);
    LDB(bq1, 0, 1);
    PH_TAIL(acc01, af, bq1);
    STAGE_A(0, 0, k2);
    LDA(af, 0, 1);
    PH_TAIL(acc11, af, bq1);
    STAGE_B(0, 1, k2);
    PH_TAILV(acc10, af, bq0);
    STAGE_A(0, 1, k2);
    LDA(af, 1, 0); LDB(bq0, 1, 0);
    PH_TAIL(acc00, af, bq0);
    STAGE_B(0, 0, k2);
    LDB(bq1, 1, 1);
    PH_TAIL(acc01, af, bq1);
    STAGE_A(1, 0, k3);
    LDA(af, 1, 1);
    PH_TAIL(acc11, af, bq1);
    STAGE_B(1, 1, k3);
    PH_TAILV(acc10, af, bq0);
  }
  VMCNT(0);

  int mr = hi * 4;
  int nc = lane & 15;
  bool isf = nc & 1;
  EPI(acc00, 0, 0);
  EPI(acc01, 0, 1);
  EPI(acc11, 1, 1);
  EPI(acc10, 1, 0);
}

// ---- 4 (path A). single-pass lookback scan ------------------------------
__global__ __launch_bounds__(256) void clear_k(int* __restrict__ p) {
  int i = blockIdx.x * 256 + threadIdx.x;
  if (i < NCHUNK * NPANEL + 1) p[i] = 0;
}

// ticket v -> (chunk ci = v>>6, panel p = v&63): a block only waits on
// strictly-smaller tickets, whose blocks already started and publish their
// flag unconditionally before any waiting -> deadlock-free. Bounded spin
// with exact-recompute fallback: cannot hang even if visibility fails.
__global__ __launch_bounds__(256) void scan_fused(const unsigned int* __restrict__ U2,
                                                  const float* __restrict__ c0,
                                                  float2* __restrict__ AV,
                                                  int* __restrict__ flags,
                                                  int* __restrict__ ticket,
                                                  float* __restrict__ out) {
  __shared__ int s_ticket;
  int tid = threadIdx.x;
  if (tid == 0) s_ticket = atomicAdd(ticket, 1);
  __syncthreads();
  int v = s_ticket;
  int ci = (v >> 6) & (NCHUNK - 1);   // masked: OOB-proof even if ticket corrupt
  int p = v & (NPANEL - 1);
  int bd = (p << 8) + tid;
  int lane = tid & 63;

  // load this chunk's u column into registers (read U exactly once)
  const unsigned int* up = U2 + (size_t)ci * CHLEN * ROWELEMS + bd;
  unsigned int u[CHLEN];
#pragma unroll
  for (int t = 0; t < CHLEN; ++t) u[t] = up[(size_t)t * ROWELEMS];

  // chunk-local affine aggregate: c_end = a*c_start + vv
  float a = 1.f, vv = 0.f;
#pragma unroll
  for (int t = 0; t < CHLEN; ++t) {
    float xt = bf2f((unsigned short)(u[t] & 0xffffu));
    float f  = bf2f((unsigned short)(u[t] >> 16));
    vv = f * vv + (1.f - f) * xt;
    a = a * f;
  }
  // publish aggregate, then release flag
  {
    unsigned long long w =
        ((unsigned long long)__float_as_uint(vv) << 32) | __float_as_uint(a);
    __hip_atomic_store((unsigned long long*)&AV[(size_t)ci * ROWELEMS + bd], w,
                       __ATOMIC_RELAXED, __HIP_MEMORY_SCOPE_AGENT);
  }
  __threadfence();
  __syncthreads();
  if (tid == 0)
    __hip_atomic_store(&flags[ci * NPANEL + p], 1, __ATOMIC_RELEASE,
                       __HIP_MEMORY_SCOPE_AGENT);

  // lookback: lane l polls chunk l's flag for this panel (parallel)
  float c = c0[bd];
  if (ci > 0) {
    int done = (lane < ci) ? 0 : 1;
    long long spins = 0;
    bool timeout = false;
    while (!__all(done)) {
      if (!done)
        done = __hip_atomic_load(&flags[lane * NPANEL + p], __ATOMIC_ACQUIRE,
                                 __HIP_MEMORY_SCOPE_AGENT);
      if (++spins > (1ll << 24)) { timeout = true; break; }
    }
    __threadfence();
    if (!timeout) {
      for (int l = 0; l < ci; ++l) {
        unsigned long long w = __hip_atomic_load(
            (const unsigned long long*)&AV[(size_t)l * ROWELEMS + bd],
            __ATOMIC_RELAXED, __HIP_MEMORY_SCOPE_AGENT);
        float al = __uint_as_float((unsigned)(w & 0xffffffffull));
        float vl = __uint_as_float((unsigned)(w >> 32));
        c = al * c + vl;
      }
    } else {
      for (int l = 0; l < ci; ++l) {  // exact sequential prefix from U
        const unsigned int* vp = U2 + (size_t)l * CHLEN * ROWELEMS + bd;
        for (int t = 0; t < CHLEN; ++t) {
          unsigned int w = vp[(size_t)t * ROWELEMS];
          float xt = bf2f((unsigned short)(w & 0xffffu));
          float f  = bf2f((unsigned short)(w >> 16));
          c = (c - xt) * f + xt;
        }
      }
    }
  }

  // replay from registers; write h
  float* op = out + (size_t)ci * CHLEN * ROWELEMS + bd;
#pragma unroll
  for (int t = 0; t < CHLEN; ++t) {
    float xt = bf2f((unsigned short)(u[t] & 0xffffu));
    float f  = bf2f((unsigned short)(u[t] >> 16));
    c = (c - xt) * f + xt;
    op[(size_t)t * ROWELEMS] = fast_tanh(c);
  }
  if (ci == NCHUNK - 1) out[(size_t)MROWS * NOUT + bd] = c;  // c_final
}

// ---- 4 (path B, fallback). R4-proven 3-kernel scan ----------------------
__global__ __launch_bounds__(256) void scan_p1(const unsigned int* __restrict__ U2,
                                               float2* __restrict__ AV) {
  int tid = threadIdx.x;
  int bid = blockIdx.x;
  int bd = ((bid >> 7) << 10) + ((bid & 3) << 8) + tid;
  int chunk = (bid >> 2) & 31;
  const unsigned int* up = U2 + (size_t)chunk * CHLEN * ROWELEMS + bd;
  float a = 1.f, v = 0.f;
  for (int t0 = 0; t0 < CHLEN; t0 += 8) {
    unsigned int w[8];
#pragma unroll
    for (int j = 0; j < 8; ++j) w[j] = up[(size_t)(t0 + j) * ROWELEMS];
#pragma unroll
    for (int j = 0; j < 8; ++j) {
      float xt = bf2f((unsigned short)(w[j] & 0xffffu));
      float f  = bf2f((unsigned short)(w[j] >> 16));
      v = f * v + (1.f - f) * xt;
      a = a * f;
    }
  }
  AV[(size_t)chunk * ROWELEMS + bd] = make_float2(a, v);
}

__global__ __launch_bounds__(256) void scan_p2(const float2* __restrict__ AV,
                                               const float* __restrict__ c0,
                                               float* __restrict__ CS,
                                               float* __restrict__ out) {
  int bd = blockIdx.x * 256 + threadIdx.x;
  float c = c0[bd];
  float2 av[NCHUNK];
#pragma unroll
  for (int k = 0; k < NCHUNK; ++k) av[k] = AV[(size_t)k * ROWELEMS + bd];
#pragma unroll
  for (int k = 0; k < NCHUNK; ++k) {
    CS[(size_t)k * ROWELEMS + bd] = c;
    c = av[k].x * c + av[k].y;
  }
  out[(size_t)MROWS * NOUT + bd] = c;
}

__global__ __launch_bounds__(256) void scan_p3(const unsigned int* __restrict__ U2,
                                               const float* __restrict__ CS,
                                               float* __restrict__ out) {
  int tid = threadIdx.x;
  int bid = blockIdx.x;
  int bd = ((bid >> 7) << 10) + ((bid & 3) << 8) + tid;
  int chunk = (bid >> 2) & 31;
  float c = CS[(size_t)chunk * ROWELEMS + bd];
  const unsigned int* up = U2 + (size_t)chunk * CHLEN * ROWELEMS + bd;
  float* op = out + (size_t)chunk * CHLEN * ROWELEMS + bd;
  for (int t0 = 0; t0 < CHLEN; t0 += 8) {
    unsigned int w[8];
#pragma unroll
    for (int j = 0; j < 8; ++j) w[j] = up[(size_t)(t0 + j) * ROWELEMS];
#pragma unroll
    for (int j = 0; j < 8; ++j) {
      float xt = bf2f((unsigned short)(w[j] & 0xffffu));
      float f  = bf2f((unsigned short)(w[j] >> 16));
      c = (c - xt) * f + xt;
      op[(size_t)(t0 + j) * ROWELEMS] = fast_tanh(c);
    }
  }
}

extern "C" void kernel_launch(void* const* d_in, const int* in_sizes, int n_in,
                              void* d_out, int out_size, void* d_ws, size_t ws_size,
                              hipStream_t stream) {
  const float* x    = (const float*)d_in[0];
  const float* c0   = (const float*)d_in[1];
  const float* W    = (const float*)d_in[2];
  const float* bias = (const float*)d_in[3];
  float* out = (float*)d_out;

  char* ws = (char*)d_ws;
  unsigned short* Abf = (unsigned short*)ws;                          // 64 MB
  unsigned short* Bp  = (unsigned short*)(ws + ((size_t)64 << 20));   // 4 MB
  unsigned short* U   = (unsigned short*)(ws + ((size_t)68 << 20));   // 128 MB

  const size_t HIGH = (size_t)196 << 20;                  // above U
  bool lookback = ws_size >= HIGH + ((size_t)4 << 20) + 16384;

  cvt_x_k<<<MROWS * NIN / (256 * 8), 256, 0, stream>>>(x, Abf);
  pack_w_k<<<dim3(NCOLS / 64, NIN / 64), 256, 0, stream>>>(W, Bp);
  gemm8_k<<<1024, 512, 0, stream>>>(Abf, Bp, bias, U);

  if (lookback) {
    float2* AV  = (float2*)(ws + HIGH);                               // 4 MB
    int* flags  = (int*)(ws + HIGH + ((size_t)4 << 20));              // 8 KB
    int* ticket = flags + NCHUNK * NPANEL;
    clear_k<<<9, 256, 0, stream>>>(flags);  // safe: region touched by no other kernel
    scan_fused<<<NCHUNK * NPANEL, 256, 0, stream>>>((const unsigned int*)U, c0,
                                                    AV, flags, ticket, out);
  } else {
    float2* AV = (float2*)ws;                      // Abf dead after gemm (R4 path)
    float*  CS = (float*)(ws + ((size_t)4 << 20));
    scan_p1<<<2048, 256, 0, stream>>>((const unsigned int*)U, AV);
    scan_p2<<<64, 256, 0, stream>>>(AV, c0, CS, out);
    scan_p3<<<2048, 256, 0, stream>>>((const unsigned int*)U, CS, out);
  }
}

// Round 8
// 254.169 us; speedup vs baseline: 3.1088x; 3.1088x over previous
//
#include <hip/hip_runtime.h>

// SRU forward: u = x@W (only k=0,1 columns), f = sigmoid(u1+bias), scan
// c_t = (c_{t-1}-x~)*f + x~, h = tanh(c). Outputs: h (L,B,N) then c_final (B,N).
//
// GEMM: 256x256 tile, BK=64, 8-phase schedule (T2 swizzle + counted vmcnt at
// ph4/ph8 tails + setprio) -- byte-identical to the R4 build that passed at
// 144 us / 0 bank conflicts. Scan: R4-proven 3-kernel chunked affine scan
// (single-pass lookback was measured 650 us -- sync-stall-bound -- reverted).
//
// ws layout: [0,64MB) A_bf16 (32768x1024)  -- dead after gemm, reused:
//            [0,4MB) AV per-chunk affine; [4,6MB) CS chunk-start c
//            [64,68MB) Bp bf16 (2048x1024 B^T, cols interleaved n=2d+j)
//            [68,196MB) U bf16 (32768x2048)

typedef __attribute__((ext_vector_type(8))) short short8;
typedef __attribute__((ext_vector_type(4))) float f32x4;

#define L_SEQ 2048
#define BATCH 16
#define NIN   1024
#define NOUT  1024
#define MROWS (L_SEQ * BATCH)    // 32768
#define NCOLS (2 * NOUT)         // 2048
#define ROWELEMS (BATCH * NOUT)  // 16384
#define NCHUNK 32
#define CHLEN  64
#define NT 16                    // K-tiles of 64 (K=1024)

__device__ __forceinline__ unsigned short f2bf(float f) {
  unsigned u = __float_as_uint(f);
  u += 0x7fffu + ((u >> 16) & 1u);
  return (unsigned short)(u >> 16);
}
__device__ __forceinline__ float bf2f(unsigned short b) {
  return __uint_as_float(((unsigned)b) << 16);
}
__device__ __forceinline__ float sigmoidf_(float x) {
  return __builtin_amdgcn_rcpf(1.f + __expf(-x));
}
__device__ __forceinline__ float fast_tanh(float x) {
  float ax = fabsf(x);
  float t = __expf(-2.f * ax);
  float r = (1.f - t) * __builtin_amdgcn_rcpf(1.f + t);
  return copysignf(r, x);
}

#define GLL16(gptr, lptr)                                              \
  __builtin_amdgcn_global_load_lds(                                    \
      (const __attribute__((address_space(1))) void*)(gptr),           \
      (__attribute__((address_space(3))) void*)(lptr), 16, 0, 0)

// ---- 1. x fp32 -> bf16 --------------------------------------------------
__global__ __launch_bounds__(256) void cvt_x_k(const float* __restrict__ x,
                                               unsigned short* __restrict__ o) {
  size_t i = ((size_t)blockIdx.x * 256 + threadIdx.x) * 8;
  const float4* p = (const float4*)(x + i);
  float4 a = p[0], b = p[1];
  union { unsigned short s[8]; uint4 v; } r;
  r.s[0] = f2bf(a.x); r.s[1] = f2bf(a.y); r.s[2] = f2bf(a.z); r.s[3] = f2bf(a.w);
  r.s[4] = f2bf(b.x); r.s[5] = f2bf(b.y); r.s[6] = f2bf(b.z); r.s[7] = f2bf(b.w);
  *(uint4*)(o + i) = r.v;
}

// ---- 2. pack W cols {3d,3d+1} -> B^T [n][k], LDS transpose (coalesced) --
__global__ __launch_bounds__(256) void pack_w_k(const float* __restrict__ W,
                                                unsigned short* __restrict__ Bp) {
  __shared__ float tile[64][97];
  int n0 = blockIdx.x * 64;
  int k0 = blockIdx.y * 64;
  int c0 = 3 * (n0 >> 1);         // col window [c0, c0+96)
  int tid = threadIdx.x;
  for (int idx = tid; idx < 64 * 96; idx += 256) {
    int r = idx / 96, c = idx - r * 96;
    tile[r][c] = W[(size_t)(k0 + r) * (3 * NOUT) + c0 + c];
  }
  __syncthreads();
#pragma unroll
  for (int q = 0; q < 2; ++q) {
    int pos = tid * 2 + q;        // 0..511; (n-row, k-chunk) pairs
    int dn = pos >> 3;
    int j8 = (pos & 7) * 8;
    int cl = 3 * (dn >> 1) + (dn & 1);
    union { unsigned short s[8]; uint4 v; } r;
#pragma unroll
    for (int j = 0; j < 8; ++j) r.s[j] = f2bf(tile[j8 + j][cl]);
    *(uint4*)(Bp + (size_t)(n0 + dn) * NIN + k0 + j8) = r.v;
  }
}

// ---- 3. 256x256 8-phase MFMA GEMM (identical to passing R4 version) -----
#define BARR __builtin_amdgcn_s_barrier()
#define SCHED0 __builtin_amdgcn_sched_barrier(0)
#define VMCNT(n) asm volatile("s_waitcnt vmcnt(" #n ")" ::: "memory")

#define STAGE_A(bufc, ha, kt)                                                   \
  do {                                                                          \
    GLL16(pga##ha##0 + (kt) * 64, lds + (bufc) * 32768 + (ha) * 16384 + tid * 16);      \
    GLL16(pga##ha##1 + (kt) * 64, lds + (bufc) * 32768 + (ha) * 16384 + 8192 + tid * 16); \
  } while (0)
#define STAGE_B(bufc, hb, kt)                                                   \
  do {                                                                          \
    GLL16(pgb##hb##0 + (kt) * 64, lds + 65536 + (bufc) * 32768 + (hb) * 16384 + tid * 16); \
    GLL16(pgb##hb##1 + (kt) * 64, lds + 65536 + (bufc) * 32768 + (hb) * 16384 + 8192 + tid * 16); \
  } while (0)

#define LDA(DST, bufc, half)                                                    \
  _Pragma("unroll") for (int i = 0; i < 4; ++i) {                               \
    DST[i][0] = *(const short8*)(lds + (bufc) * 32768 + (half) * 16384 +        \
                                 (rowAb + i * 16) * 128 + colX0);               \
    DST[i][1] = *(const short8*)(lds + (bufc) * 32768 + (half) * 16384 +        \
                                 (rowAb + i * 16) * 128 + colX1);               \
  }
#define LDB(DST, bufc, half)                                                    \
  _Pragma("unroll") for (int j = 0; j < 2; ++j) {                               \
    DST[j][0] = *(const short8*)(lds + 65536 + (bufc) * 32768 + (half) * 16384 + \
                                 (rowBb + j * 16) * 128 + colX0);               \
    DST[j][1] = *(const short8*)(lds + 65536 + (bufc) * 32768 + (half) * 16384 + \
                                 (rowBb + j * 16) * 128 + colX1);               \
  }

#define MM(Q, AF, BF)                                                           \
  _Pragma("unroll") for (int i = 0; i < 4; ++i)                                 \
  _Pragma("unroll") for (int j = 0; j < 2; ++j) {                               \
    Q[i][j] = __builtin_amdgcn_mfma_f32_16x16x32_bf16(AF[i][0], BF[j][0], Q[i][j], 0, 0, 0); \
    Q[i][j] = __builtin_amdgcn_mfma_f32_16x16x32_bf16(AF[i][1], BF[j][1], Q[i][j], 0, 0, 0); \
  }

#define PH_TAIL(Q, AF, BF)                                                      \
  BARR;                                                                         \
  __builtin_amdgcn_s_setprio(1);                                                \
  MM(Q, AF, BF);                                                                \
  __builtin_amdgcn_s_setprio(0);                                                \
  BARR;                                                                         \
  SCHED0

#define PH_TAILV(Q, AF, BF)                                                     \
  BARR;                                                                         \
  __builtin_amdgcn_s_setprio(1);                                                \
  MM(Q, AF, BF);                                                                \
  __builtin_amdgcn_s_setprio(0);                                                \
  VMCNT(4);                                                                     \
  BARR;                                                                         \
  SCHED0

#define EPI(Q, qm, qn)                                                          \
  do {                                                                          \
    _Pragma("unroll") for (int i = 0; i < 4; ++i)                               \
    _Pragma("unroll") for (int j = 0; j < 2; ++j) {                             \
      int n = n0 + (qn) * 128 + wn * 32 + j * 16 + nc;                          \
      float bsel = bias[n >> 1];                                                \
      _Pragma("unroll") for (int r = 0; r < 4; ++r) {                           \
        int m = m0 + (qm) * 128 + wm * 64 + i * 16 + mr + r;                    \
        float v = Q[i][j][r];                                                   \
        if (isf) v = sigmoidf_(v + bsel);                                       \
        U[(size_t)m * NCOLS + n] = f2bf(v);                                     \
      }                                                                         \
    }                                                                           \
  } while (0)

__global__ __launch_bounds__(512, 2) void gemm8_k(const unsigned short* __restrict__ A,
                                                  const unsigned short* __restrict__ B,
                                                  const float* __restrict__ bias,
                                                  unsigned short* __restrict__ U) {
  __shared__ __align__(16) char lds[131072];
  const int K = NIN;
  int tid = threadIdx.x;
  int wave = tid >> 6;
  int lane = tid & 63;
  int wm = wave >> 2;
  int wn = wave & 3;
  int lr = lane & 15;
  int hi = lane >> 4;

  int bi = blockIdx.x;
  int t = (bi & 7) * 128 + (bi >> 3);
  int n0 = (t & 7) << 8;
  int m0 = (t >> 3) << 8;

  int rowAb = wm * 64 + lr;
  int rowBb = wn * 32 + lr;
  int swz = (lr & 7) << 4;
  int colX0 = (hi * 16) ^ swz;
  int colX1 = (64 + hi * 16) ^ swz;

  int row0 = tid >> 3;
  int gch = (tid & 7) ^ (row0 & 7);
  const unsigned short* pga00 = A + (size_t)(m0 + row0) * K + gch * 8;
  const unsigned short* pga01 = pga00 + (size_t)64 * K;
  const unsigned short* pga10 = pga00 + (size_t)128 * K;
  const unsigned short* pga11 = pga00 + (size_t)192 * K;
  const unsigned short* pgb00 = B + (size_t)(n0 + row0) * K + gch * 8;
  const unsigned short* pgb01 = pgb00 + (size_t)64 * K;
  const unsigned short* pgb10 = pgb00 + (size_t)128 * K;
  const unsigned short* pgb11 = pgb00 + (size_t)192 * K;

  f32x4 zero = {0.f, 0.f, 0.f, 0.f};
  f32x4 acc00[4][2], acc01[4][2], acc11[4][2], acc10[4][2];
#pragma unroll
  for (int i = 0; i < 4; ++i)
#pragma unroll
    for (int j = 0; j < 2; ++j) {
      acc00[i][j] = zero; acc01[i][j] = zero;
      acc11[i][j] = zero; acc10[i][j] = zero;
    }

  short8 af[4][2], bq0[2][2], bq1[2][2];

  STAGE_A(0, 0, 0); STAGE_A(0, 1, 0); STAGE_B(0, 0, 0); STAGE_B(0, 1, 0);
  STAGE_A(1, 0, 1); STAGE_B(1, 1, 1);
  VMCNT(4);
  BARR;
  SCHED0;

  for (int it = 0; it < NT / 2; ++it) {
    int kt = it * 2;
    int k1 = kt + 1, k2 = (kt + 2) & (NT - 1), k3 = (kt + 3) & (NT - 1);
    STAGE_B(1, 0, k1); STAGE_A(1, 1, k1);
    LDA(af, 0, 0); LDB(bq0, 0, 0);
    PH_TAIL(acc00, af, bq0);
    LDB(bq1, 0, 1);
    PH_TAIL(acc01, af, bq1);
    STAGE_A(0, 0, k2);
    LDA(af, 0, 1);
    PH_TAIL(acc11, af, bq1);
    STAGE_B(0, 1, k2);
    PH_TAILV(acc10, af, bq0);
    STAGE_A(0, 1, k2);
    LDA(af, 1, 0); LDB(bq0, 1, 0);
    PH_TAIL(acc00, af, bq0);
    STAGE_B(0, 0, k2);
    LDB(bq1, 1, 1);
    PH_TAIL(acc01, af, bq1);
    STAGE_A(1, 0, k3);
    LDA(af, 1, 1);
    PH_TAIL(acc11, af, bq1);
    STAGE_B(1, 1, k3);
    PH_TAILV(acc10, af, bq0);
  }
  VMCNT(0);

  int mr = hi * 4;
  int nc = lane & 15;
  bool isf = nc & 1;
  EPI(acc00, 0, 0);
  EPI(acc01, 0, 1);
  EPI(acc11, 1, 1);
  EPI(acc10, 1, 0);
}

// ---- 4a. per-chunk affine: c_end = a*c_start + v ------------------------
__global__ __launch_bounds__(256) void scan_p1(const unsigned int* __restrict__ U2,
                                               float2* __restrict__ AV) {
  int tid = threadIdx.x;
  int bid = blockIdx.x;  // 2048 = 16 b * 32 chunk * 4 dblk
  int bd = ((bid >> 7) << 10) + ((bid & 3) << 8) + tid;
  int chunk = (bid >> 2) & 31;
  const unsigned int* up = U2 + (size_t)chunk * CHLEN * ROWELEMS + bd;
  float a = 1.f, v = 0.f;
  for (int t0 = 0; t0 < CHLEN; t0 += 8) {
    unsigned int w[8];
#pragma unroll
    for (int j = 0; j < 8; ++j) w[j] = up[(size_t)(t0 + j) * ROWELEMS];
#pragma unroll
    for (int j = 0; j < 8; ++j) {
      float xt = bf2f((unsigned short)(w[j] & 0xffffu));
      float f  = bf2f((unsigned short)(w[j] >> 16));
      v = f * v + (1.f - f) * xt;
      a = a * f;
    }
  }
  AV[(size_t)chunk * ROWELEMS + bd] = make_float2(a, v);
}

// ---- 4b. scan chunk boundaries; emit c_final ----------------------------
__global__ __launch_bounds__(256) void scan_p2(const float2* __restrict__ AV,
                                               const float* __restrict__ c0,
                                               float* __restrict__ CS,
                                               float* __restrict__ out) {
  int bd = blockIdx.x * 256 + threadIdx.x;
  float c = c0[bd];
  float2 av[NCHUNK];
#pragma unroll
  for (int k = 0; k < NCHUNK; ++k) av[k] = AV[(size_t)k * ROWELEMS + bd];
#pragma unroll
  for (int k = 0; k < NCHUNK; ++k) {
    CS[(size_t)k * ROWELEMS + bd] = c;
    c = av[k].x * c + av[k].y;
  }
  out[(size_t)MROWS * NOUT + bd] = c;
}

// ---- 4c. replay each chunk exactly from corrected start; write h --------
__global__ __launch_bounds__(256) void scan_p3(const unsigned int* __restrict__ U2,
                                               const float* __restrict__ CS,
                                               float* __restrict__ out) {
  int tid = threadIdx.x;
  int bid = blockIdx.x;
  int bd = ((bid >> 7) << 10) + ((bid & 3) << 8) + tid;
  int chunk = (bid >> 2) & 31;
  float c = CS[(size_t)chunk * ROWELEMS + bd];
  const unsigned int* up = U2 + (size_t)chunk * CHLEN * ROWELEMS + bd;
  float* op = out + (size_t)chunk * CHLEN * ROWELEMS + bd;
  for (int t0 = 0; t0 < CHLEN; t0 += 8) {
    unsigned int w[8];
#pragma unroll
    for (int j = 0; j < 8; ++j) w[j] = up[(size_t)(t0 + j) * ROWELEMS];
#pragma unroll
    for (int j = 0; j < 8; ++j) {
      float xt = bf2f((unsigned short)(w[j] & 0xffffu));
      float f  = bf2f((unsigned short)(w[j] >> 16));
      c = (c - xt) * f + xt;
      op[(size_t)(t0 + j) * ROWELEMS] = fast_tanh(c);
    }
  }
}

extern "C" void kernel_launch(void* const* d_in, const int* in_sizes, int n_in,
                              void* d_out, int out_size, void* d_ws, size_t ws_size,
                              hipStream_t stream) {
  const float* x    = (const float*)d_in[0];
  const float* c0   = (const float*)d_in[1];
  const float* W    = (const float*)d_in[2];
  const float* bias = (const float*)d_in[3];
  float* out = (float*)d_out;

  char* ws = (char*)d_ws;
  unsigned short* Abf = (unsigned short*)ws;                          // 64 MB
  unsigned short* Bp  = (unsigned short*)(ws + ((size_t)64 << 20));   // 4 MB
  unsigned short* U   = (unsigned short*)(ws + ((size_t)68 << 20));   // 128 MB
  float2* AV = (float2*)ws;                      // Abf dead after gemm
  float*  CS = (float*)(ws + ((size_t)4 << 20));

  cvt_x_k<<<MROWS * NIN / (256 * 8), 256, 0, stream>>>(x, Abf);
  pack_w_k<<<dim3(NCOLS / 64, NIN / 64), 256, 0, stream>>>(W, Bp);
  gemm8_k<<<1024, 512, 0, stream>>>(Abf, Bp, bias, U);
  scan_p1<<<2048, 256, 0, stream>>>((const unsigned int*)U, AV);
  scan_p2<<<64, 256, 0, stream>>>(AV, c0, CS, out);
  scan_p3<<<2048, 256, 0, stream>>>((const unsigned int*)U, CS, out);
}

// Round 9
// 251.104 us; speedup vs baseline: 3.1468x; 1.0122x over previous
//
#include <hip/hip_runtime.h>

// SRU forward: u = x@W (only k=0,1 columns), f = sigmoid(u1+bias), scan
// c_t = (c_{t-1}-x~)*f + x~, h = tanh(c). Outputs: h (L,B,N) then c_final (B,N).
//
// GEMM: 256x256 tile, BK=64, 4-phase schedule (merged from the proven R4
// 8-phase: same stage/read issue order => same vmcnt algebra, half the
// barriers). Last iteration peeled: no wrap staging, vmcnt(0) once.
// Scan: R4-proven 3-kernel chunked affine scan.
//
// ws layout: [0,64MB) A_bf16 (32768x1024)  -- dead after gemm, reused:
//            [0,4MB) AV per-chunk affine; [4,6MB) CS chunk-start c
//            [64,68MB) Bp bf16 (2048x1024 B^T, cols interleaved n=2d+j)
//            [68,196MB) U bf16 (32768x2048)

typedef __attribute__((ext_vector_type(8))) short short8;
typedef __attribute__((ext_vector_type(4))) float f32x4;

#define L_SEQ 2048
#define BATCH 16
#define NIN   1024
#define NOUT  1024
#define MROWS (L_SEQ * BATCH)    // 32768
#define NCOLS (2 * NOUT)         // 2048
#define ROWELEMS (BATCH * NOUT)  // 16384
#define NCHUNK 32
#define CHLEN  64
#define NT 16                    // K-tiles of 64 (K=1024)

__device__ __forceinline__ unsigned short f2bf(float f) {
  unsigned u = __float_as_uint(f);
  u += 0x7fffu + ((u >> 16) & 1u);
  return (unsigned short)(u >> 16);
}
__device__ __forceinline__ float bf2f(unsigned short b) {
  return __uint_as_float(((unsigned)b) << 16);
}
__device__ __forceinline__ float sigmoidf_(float x) {
  return __builtin_amdgcn_rcpf(1.f + __expf(-x));
}
__device__ __forceinline__ float fast_tanh(float x) {
  float ax = fabsf(x);
  float t = __expf(-2.f * ax);
  float r = (1.f - t) * __builtin_amdgcn_rcpf(1.f + t);
  return copysignf(r, x);
}

#define GLL16(gptr, lptr)                                              \
  __builtin_amdgcn_global_load_lds(                                    \
      (const __attribute__((address_space(1))) void*)(gptr),           \
      (__attribute__((address_space(3))) void*)(lptr), 16, 0, 0)

// ---- 1. x fp32 -> bf16 --------------------------------------------------
__global__ __launch_bounds__(256) void cvt_x_k(const float* __restrict__ x,
                                               unsigned short* __restrict__ o) {
  size_t i = ((size_t)blockIdx.x * 256 + threadIdx.x) * 8;
  const float4* p = (const float4*)(x + i);
  float4 a = p[0], b = p[1];
  union { unsigned short s[8]; uint4 v; } r;
  r.s[0] = f2bf(a.x); r.s[1] = f2bf(a.y); r.s[2] = f2bf(a.z); r.s[3] = f2bf(a.w);
  r.s[4] = f2bf(b.x); r.s[5] = f2bf(b.y); r.s[6] = f2bf(b.z); r.s[7] = f2bf(b.w);
  *(uint4*)(o + i) = r.v;
}

// ---- 2. pack W cols {3d,3d+1} -> B^T [n][k], LDS transpose (coalesced) --
__global__ __launch_bounds__(256) void pack_w_k(const float* __restrict__ W,
                                                unsigned short* __restrict__ Bp) {
  __shared__ float tile[64][97];
  int n0 = blockIdx.x * 64;
  int k0 = blockIdx.y * 64;
  int c0 = 3 * (n0 >> 1);         // col window [c0, c0+96)
  int tid = threadIdx.x;
  for (int idx = tid; idx < 64 * 96; idx += 256) {
    int r = idx / 96, c = idx - r * 96;
    tile[r][c] = W[(size_t)(k0 + r) * (3 * NOUT) + c0 + c];
  }
  __syncthreads();
#pragma unroll
  for (int q = 0; q < 2; ++q) {
    int pos = tid * 2 + q;        // 0..511; (n-row, k-chunk) pairs
    int dn = pos >> 3;
    int j8 = (pos & 7) * 8;
    int cl = 3 * (dn >> 1) + (dn & 1);
    union { unsigned short s[8]; uint4 v; } r;
#pragma unroll
    for (int j = 0; j < 8; ++j) r.s[j] = f2bf(tile[j8 + j][cl]);
    *(uint4*)(Bp + (size_t)(n0 + dn) * NIN + k0 + j8) = r.v;
  }
}

// ---- 3. 256x256 4-phase MFMA GEMM ---------------------------------------
#define BARR __builtin_amdgcn_s_barrier()
#define SCHED0 __builtin_amdgcn_sched_barrier(0)
#define VMCNT(n) asm volatile("s_waitcnt vmcnt(" #n ")" ::: "memory")

#define STAGE_A(bufc, ha, kt)                                                   \
  do {                                                                          \
    GLL16(pga##ha##0 + (kt) * 64, lds + (bufc) * 32768 + (ha) * 16384 + tid * 16);      \
    GLL16(pga##ha##1 + (kt) * 64, lds + (bufc) * 32768 + (ha) * 16384 + 8192 + tid * 16); \
  } while (0)
#define STAGE_B(bufc, hb, kt)                                                   \
  do {                                                                          \
    GLL16(pgb##hb##0 + (kt) * 64, lds + 65536 + (bufc) * 32768 + (hb) * 16384 + tid * 16); \
    GLL16(pgb##hb##1 + (kt) * 64, lds + 65536 + (bufc) * 32768 + (hb) * 16384 + 8192 + tid * 16); \
  } while (0)

#define LDA(DST, bufc, half)                                                    \
  _Pragma("unroll") for (int i = 0; i < 4; ++i) {                               \
    DST[i][0] = *(const short8*)(lds + (bufc) * 32768 + (half) * 16384 +        \
                                 (rowAb + i * 16) * 128 + colX0);               \
    DST[i][1] = *(const short8*)(lds + (bufc) * 32768 + (half) * 16384 +        \
                                 (rowAb + i * 16) * 128 + colX1);               \
  }
#define LDB(DST, bufc, half)                                                    \
  _Pragma("unroll") for (int j = 0; j < 2; ++j) {                               \
    DST[j][0] = *(const short8*)(lds + 65536 + (bufc) * 32768 + (half) * 16384 + \
                                 (rowBb + j * 16) * 128 + colX0);               \
    DST[j][1] = *(const short8*)(lds + 65536 + (bufc) * 32768 + (half) * 16384 + \
                                 (rowBb + j * 16) * 128 + colX1);               \
  }

#define MM(Q, AF, BF)                                                           \
  _Pragma("unroll") for (int i = 0; i < 4; ++i)                                 \
  _Pragma("unroll") for (int j = 0; j < 2; ++j) {                               \
    Q[i][j] = __builtin_amdgcn_mfma_f32_16x16x32_bf16(AF[i][0], BF[j][0], Q[i][j], 0, 0, 0); \
    Q[i][j] = __builtin_amdgcn_mfma_f32_16x16x32_bf16(AF[i][1], BF[j][1], Q[i][j], 0, 0, 0); \
  }

// merged phase: two C-quadrant MFMA clusters per barrier pair (32 MFMA)
#define PH2_TAIL(Q1, BF1, Q2, BF2)                                              \
  BARR;                                                                         \
  __builtin_amdgcn_s_setprio(1);                                                \
  MM(Q1, af, BF1);                                                              \
  MM(Q2, af, BF2);                                                              \
  __builtin_amdgcn_s_setprio(0);                                                \
  BARR;                                                                         \
  SCHED0

// counted vmcnt BEFORE the closing barrier (availability of the next tile)
#define PH2_TAILV(Q1, BF1, Q2, BF2)                                             \
  BARR;                                                                         \
  __builtin_amdgcn_s_setprio(1);                                                \
  MM(Q1, af, BF1);                                                              \
  MM(Q2, af, BF2);                                                              \
  __builtin_amdgcn_s_setprio(0);                                                \
  VMCNT(4);                                                                     \
  BARR;                                                                         \
  SCHED0

// full drain variant (peeled last iteration)
#define PH2_TAILV0(Q1, BF1, Q2, BF2)                                            \
  BARR;                                                                         \
  __builtin_amdgcn_s_setprio(1);                                                \
  MM(Q1, af, BF1);                                                              \
  MM(Q2, af, BF2);                                                              \
  __builtin_amdgcn_s_setprio(0);                                                \
  VMCNT(0);                                                                     \
  BARR;                                                                         \
  SCHED0

#define EPI(Q, qm, qn)                                                          \
  do {                                                                          \
    _Pragma("unroll") for (int i = 0; i < 4; ++i)                               \
    _Pragma("unroll") for (int j = 0; j < 2; ++j) {                             \
      int n = n0 + (qn) * 128 + wn * 32 + j * 16 + nc;                          \
      float bsel = bias[n >> 1];                                                \
      _Pragma("unroll") for (int r = 0; r < 4; ++r) {                           \
        int m = m0 + (qm) * 128 + wm * 64 + i * 16 + mr + r;                    \
        float v = Q[i][j][r];                                                   \
        if (isf) v = sigmoidf_(v + bsel);                                       \
        U[(size_t)m * NCOLS + n] = f2bf(v);                                     \
      }                                                                         \
    }                                                                           \
  } while (0)

__global__ __launch_bounds__(512, 2) void gemm8_k(const unsigned short* __restrict__ A,
                                                  const unsigned short* __restrict__ B,
                                                  const float* __restrict__ bias,
                                                  unsigned short* __restrict__ U) {
  __shared__ __align__(16) char lds[131072];
  const int K = NIN;
  int tid = threadIdx.x;
  int wave = tid >> 6;
  int lane = tid & 63;
  int wm = wave >> 2;
  int wn = wave & 3;
  int lr = lane & 15;
  int hi = lane >> 4;

  // XCD-chunked swizzle (1024 % 8 == 0)
  int bi = blockIdx.x;
  int t = (bi & 7) * 128 + (bi >> 3);
  int n0 = (t & 7) << 8;
  int m0 = (t >> 3) << 8;

  // LDS read addressing (T2 swizzle: byte-col ^= (row&7)<<4)
  int rowAb = wm * 64 + lr;
  int rowBb = wn * 32 + lr;
  int swz = (lr & 7) << 4;
  int colX0 = (hi * 16) ^ swz;
  int colX1 = (64 + hi * 16) ^ swz;

  // staging source (inverse-swizzled global chunk, linear LDS dest)
  int row0 = tid >> 3;
  int gch = (tid & 7) ^ (row0 & 7);
  const unsigned short* pga00 = A + (size_t)(m0 + row0) * K + gch * 8;
  const unsigned short* pga01 = pga00 + (size_t)64 * K;
  const unsigned short* pga10 = pga00 + (size_t)128 * K;
  const unsigned short* pga11 = pga00 + (size_t)192 * K;
  const unsigned short* pgb00 = B + (size_t)(n0 + row0) * K + gch * 8;
  const unsigned short* pgb01 = pgb00 + (size_t)64 * K;
  const unsigned short* pgb10 = pgb00 + (size_t)128 * K;
  const unsigned short* pgb11 = pgb00 + (size_t)192 * K;

  f32x4 zero = {0.f, 0.f, 0.f, 0.f};
  f32x4 acc00[4][2], acc01[4][2], acc11[4][2], acc10[4][2];
#pragma unroll
  for (int i = 0; i < 4; ++i)
#pragma unroll
    for (int j = 0; j < 2; ++j) {
      acc00[i][j] = zero; acc01[i][j] = zero;
      acc11[i][j] = zero; acc10[i][j] = zero;
    }

  short8 af[4][2], bq0[2][2], bq1[2][2];

  // prologue: tile0 complete + tile1 {A0, B1}; invariant: 4 loads in flight
  STAGE_A(0, 0, 0); STAGE_A(0, 1, 0); STAGE_B(0, 0, 0); STAGE_B(0, 1, 0);
  STAGE_A(1, 0, 1); STAGE_B(1, 1, 1);
  VMCNT(4);
  BARR;
  SCHED0;

  // main loop: tiles 0..13 (issue order identical to the proven 8-phase)
  for (int it = 0; it < NT / 2 - 1; ++it) {
    int kt = it * 2;
    int k1 = kt + 1, k2 = kt + 2, k3 = kt + 3;
    // P1 (= old ph1+ph2): complete tile k1 staging; compute buf0 x half0 quads
    STAGE_B(1, 0, k1); STAGE_A(1, 1, k1);
    LDA(af, 0, 0); LDB(bq0, 0, 0); LDB(bq1, 0, 1);
    PH2_TAIL(acc00, bq0, acc01, bq1);
    // P2 (= old ph3+ph4): stage k2.{A0,B1}; vmcnt(4) retires tile k1
    STAGE_A(0, 0, k2); STAGE_B(0, 1, k2);
    LDA(af, 0, 1);
    PH2_TAILV(acc11, bq1, acc10, bq0);
    // P3 (= old ph5+ph6): stage k2.{A1,B0}; compute buf1 (tile k1)
    STAGE_A(0, 1, k2); STAGE_B(0, 0, k2);
    LDA(af, 1, 0); LDB(bq0, 1, 0); LDB(bq1, 1, 1);
    PH2_TAIL(acc00, bq0, acc01, bq1);
    // P4 (= old ph7+ph8): stage k3.{A0,B1}; vmcnt(4) retires tile k2
    STAGE_A(1, 0, k3); STAGE_B(1, 1, k3);
    LDA(af, 1, 1);
    PH2_TAILV(acc11, bq1, acc10, bq0);
  }

  // peeled last iteration: tiles 14,15 -- no wrap staging
  {
    // P1: complete tile 15 staging
    STAGE_B(1, 0, 15); STAGE_A(1, 1, 15);
    LDA(af, 0, 0); LDB(bq0, 0, 0); LDB(bq1, 0, 1);
    PH2_TAIL(acc00, bq0, acc01, bq1);
    // P2: no stage; vmcnt(0) -> tile 15 fully landed
    LDA(af, 0, 1);
    PH2_TAILV0(acc11, bq1, acc10, bq0);
    // P3: compute tile 15
    LDA(af, 1, 0); LDB(bq0, 1, 0); LDB(bq1, 1, 1);
    PH2_TAIL(acc00, bq0, acc01, bq1);
    // P4
    LDA(af, 1, 1);
    PH2_TAIL(acc11, bq1, acc10, bq0);
  }

  // epilogue: C/D map col=lane&15, row=(lane>>4)*4+reg
  int mr = hi * 4;
  int nc = lane & 15;
  bool isf = nc & 1;
  EPI(acc00, 0, 0);
  EPI(acc01, 0, 1);
  EPI(acc11, 1, 1);
  EPI(acc10, 1, 0);
}

// ---- 4a. per-chunk affine: c_end = a*c_start + v ------------------------
__global__ __launch_bounds__(256) void scan_p1(const unsigned int* __restrict__ U2,
                                               float2* __restrict__ AV) {
  int tid = threadIdx.x;
  int bid = blockIdx.x;  // 2048 = 16 b * 32 chunk * 4 dblk
  int bd = ((bid >> 7) << 10) + ((bid & 3) << 8) + tid;
  int chunk = (bid >> 2) & 31;
  const unsigned int* up = U2 + (size_t)chunk * CHLEN * ROWELEMS + bd;
  float a = 1.f, v = 0.f;
  for (int t0 = 0; t0 < CHLEN; t0 += 8) {
    unsigned int w[8];
#pragma unroll
    for (int j = 0; j < 8; ++j) w[j] = up[(size_t)(t0 + j) * ROWELEMS];
#pragma unroll
    for (int j = 0; j < 8; ++j) {
      float xt = bf2f((unsigned short)(w[j] & 0xffffu));
      float f  = bf2f((unsigned short)(w[j] >> 16));
      v = f * v + (1.f - f) * xt;
      a = a * f;
    }
  }
  AV[(size_t)chunk * ROWELEMS + bd] = make_float2(a, v);
}

// ---- 4b. scan chunk boundaries; emit c_final ----------------------------
__global__ __launch_bounds__(256) void scan_p2(const float2* __restrict__ AV,
                                               const float* __restrict__ c0,
                                               float* __restrict__ CS,
                                               float* __restrict__ out) {
  int bd = blockIdx.x * 256 + threadIdx.x;
  float c = c0[bd];
  float2 av[NCHUNK];
#pragma unroll
  for (int k = 0; k < NCHUNK; ++k) av[k] = AV[(size_t)k * ROWELEMS + bd];
#pragma unroll
  for (int k = 0; k < NCHUNK; ++k) {
    CS[(size_t)k * ROWELEMS + bd] = c;
    c = av[k].x * c + av[k].y;
  }
  out[(size_t)MROWS * NOUT + bd] = c;
}

// ---- 4c. replay each chunk exactly from corrected start; write h --------
__global__ __launch_bounds__(256) void scan_p3(const unsigned int* __restrict__ U2,
                                               const float* __restrict__ CS,
                                               float* __restrict__ out) {
  int tid = threadIdx.x;
  int bid = blockIdx.x;
  int bd = ((bid >> 7) << 10) + ((bid & 3) << 8) + tid;
  int chunk = (bid >> 2) & 31;
  float c = CS[(size_t)chunk * ROWELEMS + bd];
  const unsigned int* up = U2 + (size_t)chunk * CHLEN * ROWELEMS + bd;
  float* op = out + (size_t)chunk * CHLEN * ROWELEMS + bd;
  for (int t0 = 0; t0 < CHLEN; t0 += 8) {
    unsigned int w[8];
#pragma unroll
    for (int j = 0; j < 8; ++j) w[j] = up[(size_t)(t0 + j) * ROWELEMS];
#pragma unroll
    for (int j = 0; j < 8; ++j) {
      float xt = bf2f((unsigned short)(w[j] & 0xffffu));
      float f  = bf2f((unsigned short)(w[j] >> 16));
      c = (c - xt) * f + xt;
      op[(size_t)(t0 + j) * ROWELEMS] = fast_tanh(c);
    }
  }
}

extern "C" void kernel_launch(void* const* d_in, const int* in_sizes, int n_in,
                              void* d_out, int out_size, void* d_ws, size_t ws_size,
                              hipStream_t stream) {
  const float* x    = (const float*)d_in[0];
  const float* c0   = (const float*)d_in[1];
  const float* W    = (const float*)d_in[2];
  const float* bias = (const float*)d_in[3];
  float* out = (float*)d_out;

  char* ws = (char*)d_ws;
  unsigned short* Abf = (unsigned short*)ws;                          // 64 MB
  unsigned short* Bp  = (unsigned short*)(ws + ((size_t)64 << 20));   // 4 MB
  unsigned short* U   = (unsigned short*)(ws + ((size_t)68 << 20));   // 128 MB
  float2* AV = (float2*)ws;                      // Abf dead after gemm
  float*  CS = (float*)(ws + ((size_t)4 << 20));

  cvt_x_k<<<MROWS * NIN / (256 * 8), 256, 0, stream>>>(x, Abf);
  pack_w_k<<<dim3(NCOLS / 64, NIN / 64), 256, 0, stream>>>(W, Bp);
  gemm8_k<<<1024, 512, 0, stream>>>(Abf, Bp, bias, U);
  scan_p1<<<2048, 256, 0, stream>>>((const unsigned int*)U, AV);
  scan_p2<<<64, 256, 0, stream>>>(AV, c0, CS, out);
  scan_p3<<<2048, 256, 0, stream>>>((const unsigned int*)U, CS, out);
}